// Round 10
// baseline (720.699 us; speedup 1.0000x reference)
//
#include <hip/hip_runtime.h>
#include <math.h>

#define NTOK 8192
#define DM 1024
#define NE 8
#define DF 4096
#define MAXTILES 136   // 128-row tiles: <=128 full + <=8 partial

typedef short  s16x8 __attribute__((ext_vector_type(8)));
typedef float  f32x4 __attribute__((ext_vector_type(4)));

// ---------------- workspace layout (bytes) ----------------
#define OFF_XN      0ull                       // 8192*1024*2        = 16777216
#define OFF_W1T     16777216ull                // 8*4096*1024*2      = 67108864  (y overlays after gemm1)
#define OFF_W2T     83886080ull                // 8*1024*4096*2      = 67108864
#define OFF_H       150994944ull               // 16384*4096*2       = 134217728
#define OFF_PROBS   285212672ull               // 8192*8*4           = 262144
#define OFF_TOPI    285474816ull               // 8192*2*4           = 65536 (becomes asn rows)
#define OFF_TOPP    285540352ull               // 8192*2*4           = 65536
#define OFF_ROWTOK  285605888ull               // 16384*4            = 65536
#define OFF_ROWP    285671424ull               // 16384*4            = 65536
#define OFF_COUNTS  285736960ull               // 8*4
#define OFF_CURSORS 285736992ull               // 8*4
#define OFF_NTILES  285737024ull               // 4 (+pad)
#define OFF_TILES   285737088ull               // 136*16 = 2176
#define WS_NEEDED   285739264ull

__device__ __forceinline__ unsigned short f2bf(float f) {
  unsigned u = __builtin_bit_cast(unsigned, f);
  u += 0x7fffu + ((u >> 16) & 1u);
  return (unsigned short)(u >> 16);
}
__device__ __forceinline__ float bf2f(unsigned short s) {
  unsigned u = ((unsigned)s) << 16;
  return __builtin_bit_cast(float, u);
}

__device__ __forceinline__ void gload_lds16(const void* g, void* l) {
  __builtin_amdgcn_global_load_lds(
      (const __attribute__((address_space(1))) void*)g,
      (__attribute__((address_space(3))) void*)l, 16, 0, 0);
}

// XCD-aware CHUNKED item range. With gridDim >= nItems each block gets
// 0 or 1 item -> zero tail quantization; consecutive items sit on
// consecutive blocks of one XCD -> co-scheduled, L2 co-located.
__device__ __forceinline__ void chunk_range(int nItems, int* s, int* e) {
  const int xcd = blockIdx.x & 7, lnx = blockIdx.x >> 3;
  const int nbx = (int)(gridDim.x >> 3);
  const int cs = nItems >> 3, cr = nItems & 7;
  const int base = xcd * cs + (xcd < cr ? xcd : cr);
  const int csz  = cs + (xcd < cr ? 1 : 0);
  const int q = csz / nbx, r = csz % nbx;
  *s = base + lnx * q + (lnx < r ? lnx : r);
  *e = *s + q + (lnx < r ? 1 : 0);
}

// ---------------- init: zero expert counts ----------------
__global__ void init_kernel(unsigned* counts) {
  if (threadIdx.x < NE) counts[threadIdx.x] = 0u;
}

// ---------------- sentinel if ws too small ----------------
__global__ void sentinel_kernel(float* out, int n) {
  for (int i = blockIdx.x * 256 + threadIdx.x; i < n; i += 2048 * 256)
    out[i] = -12345.0f;
}

// =====================================================================
// front_kernel: heterogeneous launch, heavy transpose blocks FIRST:
//   bid <  4096          : w1 transpose-cast chunk  (e,panel,rchunk)
//   4096 <= bid < 8192   : w2 transpose-cast chunk
//   8192 <= bid < 16384  : LayerNorm + router for token (bid-8192)
// Transpose chunk = 128 rows x 64 cols: 256B-segment reads, bf16-in-LDS
// (scatter on LDS-write side), 256B-aligned 16B/lane output stores;
// consecutive blocks = consecutive r-chunks of one output panel so each
// 2KB output row is filled densely by co-scheduled sibling blocks.
// =====================================================================
__global__ __launch_bounds__(256) void front_kernel(
    const float* __restrict__ x, const float* __restrict__ gamma,
    const float* __restrict__ beta, const float* __restrict__ rw,
    const float* __restrict__ rb, unsigned short* __restrict__ xnb,
    float* __restrict__ probs, int* __restrict__ topi,
    float* __restrict__ topp, unsigned* __restrict__ counts,
    const float* __restrict__ w1, unsigned short* __restrict__ w1t,
    const float* __restrict__ w2, unsigned short* __restrict__ w2t) {
  __shared__ unsigned short lt[64][132];   // 16.9 KB; ln path aliases head
  const int bid = blockIdx.x;
  const int t = threadIdx.x;

  if (bid < 8192) {
    // ---------------- transpose-cast chunk ----------------
    const float* w;
    unsigned short* wt;
    int R, C, e, panel, rc;
    if (bid < 4096) {               // w1: [E][1024][4096] -> w1t [E][4096][1024]
      w = w1; wt = w1t; R = DM; C = DF;
      e = bid >> 9;                 // 512 chunks/expert = 64 panels * 8 rchunks
      panel = (bid & 511) >> 3; rc = bid & 7;
    } else {                        // w2: [E][4096][1024] -> w2t [E][1024][4096]
      const int b = bid - 4096;
      w = w2; wt = w2t; R = DF; C = DM;
      e = b >> 9;                   // 512 chunks/expert = 16 panels * 32 rchunks
      panel = (b & 511) >> 5; rc = b & 31;
    }
    const int c0 = panel << 6;      // 64 output rows (cols of w)
    const int r0 = rc << 7;         // 128 input rows
    const float* we = w + (size_t)e * R * C;
    unsigned short* wte = wt + (size_t)e * R * C;

    // phase A: read [128 r][64 c] f32 (256B/row segments), cast, scatter to lt[c][r]
#pragma unroll
    for (int s = 0; s < 8; ++s) {
      const int idx = s * 256 + t;
      const int r = idx >> 4, c4 = (idx & 15) * 4;
      float4 v = *(const float4*)(we + (size_t)(r0 + r) * C + c0 + c4);
      lt[c4][r]     = f2bf(v.x);
      lt[c4 + 1][r] = f2bf(v.y);
      lt[c4 + 2][r] = f2bf(v.z);
      lt[c4 + 3][r] = f2bf(v.w);
    }
    __syncthreads();
    // phase B: contiguous b64-pair LDS reads, 16B/lane stores (256B segments)
#pragma unroll
    for (int s = 0; s < 4; ++s) {
      const int idx = s * 256 + t;
      const int c = idx >> 4, r8 = (idx & 15) * 8;
      uint2 lo = *(const uint2*)&lt[c][r8];
      uint2 hi = *(const uint2*)&lt[c][r8 + 4];
      int4 o = make_int4((int)lo.x, (int)lo.y, (int)hi.x, (int)hi.y);
      *(int4*)(wte + (size_t)(c0 + c) * R + r0 + r8) = o;
    }
    return;
  }

  // ---------------- LayerNorm + router for token `bid-8192` ----------------
  {
    const int tok = bid - 8192;
    const int lane = t & 63, wave = t >> 6;
    float* red  = (float*)&lt[0][0];        // 16 floats
    float* lred = ((float*)&lt[0][0]) + 16; // 32 floats

    float4 xv = *(const float4*)(x + (size_t)tok * DM + t * 4);
    float s = xv.x + xv.y + xv.z + xv.w;
    float q = xv.x * xv.x + xv.y * xv.y + xv.z * xv.z + xv.w * xv.w;
    for (int o = 32; o > 0; o >>= 1) {
      s += __shfl_down(s, o);
      q += __shfl_down(q, o);
    }
    if (lane == 0) { red[wave] = s; red[8 + wave] = q; }
    __syncthreads();
    float tot  = red[0] + red[1] + red[2] + red[3];
    float totq = red[8] + red[9] + red[10] + red[11];
    float mu = tot * (1.0f / DM);
    float var = totq * (1.0f / DM) - mu * mu;
    float rstd = rsqrtf(var + 1e-5f);

    float4 g = *(const float4*)(gamma + t * 4);
    float4 b = *(const float4*)(beta + t * 4);
    float xn[4];
    xn[0] = (xv.x - mu) * rstd * g.x + b.x;
    xn[1] = (xv.y - mu) * rstd * g.y + b.y;
    xn[2] = (xv.z - mu) * rstd * g.z + b.z;
    xn[3] = (xv.w - mu) * rstd * g.w + b.w;
    ushort4 pk = { f2bf(xn[0]), f2bf(xn[1]), f2bf(xn[2]), f2bf(xn[3]) };
    *(ushort4*)(xnb + (size_t)tok * DM + t * 4) = pk;

    float a[8] = {0, 0, 0, 0, 0, 0, 0, 0};
    const float4* r4 = (const float4*)(rw + (size_t)t * 32);
#pragma unroll
    for (int j = 0; j < 4; ++j) {
      float4 lo = r4[j * 2], hi = r4[j * 2 + 1];
      a[0] += xn[j] * lo.x; a[1] += xn[j] * lo.y;
      a[2] += xn[j] * lo.z; a[3] += xn[j] * lo.w;
      a[4] += xn[j] * hi.x; a[5] += xn[j] * hi.y;
      a[6] += xn[j] * hi.z; a[7] += xn[j] * hi.w;
    }
#pragma unroll
    for (int e = 0; e < 8; ++e)
      for (int o = 32; o > 0; o >>= 1) a[e] += __shfl_down(a[e], o);
    if (lane == 0) {
#pragma unroll
      for (int e = 0; e < 8; ++e) lred[wave * 8 + e] = a[e];
    }
    __syncthreads();
    if (t == 0) {
      float lg[8], mx = -1e30f;
#pragma unroll
      for (int e = 0; e < 8; ++e) {
        lg[e] = lred[e] + lred[8 + e] + lred[16 + e] + lred[24 + e] + rb[e];
        mx = fmaxf(mx, lg[e]);
      }
      float ex[8], se = 0.f;
#pragma unroll
      for (int e = 0; e < 8; ++e) { ex[e] = expf(lg[e] - mx); se += ex[e]; }
      float inv = 1.f / se;
      float pr[8];
#pragma unroll
      for (int e = 0; e < 8; ++e) {
        pr[e] = ex[e] * inv;
        probs[tok * 8 + e] = pr[e];
      }
      int i0 = 0;
#pragma unroll
      for (int e = 1; e < 8; ++e) if (pr[e] > pr[i0]) i0 = e;
      int i1 = (i0 == 0) ? 1 : 0;
#pragma unroll
      for (int e = 0; e < 8; ++e)
        if (e != i0 && pr[e] > pr[i1]) i1 = e;
      float p0 = pr[i0], p1 = pr[i1], inv2 = 1.f / (p0 + p1);
      topi[tok * 2] = i0; topi[tok * 2 + 1] = i1;
      topp[tok * 2] = p0 * inv2; topp[tok * 2 + 1] = p1 * inv2;
      atomicAdd(&counts[i0], 1u);
      atomicAdd(&counts[i1], 1u);
    }
  }
}

// ------- plan (t0) + aux loss (all threads), one 256-thread block -------
__global__ __launch_bounds__(256) void plan_aux_kernel(
    const unsigned* __restrict__ counts, unsigned* __restrict__ cursors,
    int4* __restrict__ tiles, int* __restrict__ ntiles,
    const float* __restrict__ probs, float* __restrict__ out_aux) {
  const int t = threadIdx.x;
  if (t == 0) {
    unsigned o = 0; int nt = 0;
    for (int e = 0; e < NE; ++e) {
      cursors[e] = o;
      unsigned c = counts[e];
      for (unsigned st = 0; st < c; st += 128u) {
        unsigned nr = c - st; if (nr > 128u) nr = 128u;
        tiles[nt] = make_int4(e, (int)(o + st), (int)nr, 0);
        ++nt;
      }
      o += c;
    }
    *ntiles = nt;
  }
  float a[8] = {0, 0, 0, 0, 0, 0, 0, 0};
  for (int tok = t; tok < NTOK; tok += 256) {
    const float4* p4 = (const float4*)(probs + (size_t)tok * 8);
    float4 lo = p4[0], hi = p4[1];
    a[0] += lo.x; a[1] += lo.y; a[2] += lo.z; a[3] += lo.w;
    a[4] += hi.x; a[5] += hi.y; a[6] += hi.z; a[7] += hi.w;
  }
  const int lane = t & 63, wave = t >> 6;
#pragma unroll
  for (int e = 0; e < 8; ++e)
    for (int o = 32; o > 0; o >>= 1) a[e] += __shfl_down(a[e], o);
  __shared__ float sh[4][8];
  if (lane == 0) {
#pragma unroll
    for (int e = 0; e < 8; ++e) sh[wave][e] = a[e];
  }
  __syncthreads();
  if (t == 0) {
    float aux = 0.f;
#pragma unroll
    for (int e = 0; e < 8; ++e) {
      float load = (sh[0][e] + sh[1][e] + sh[2][e] + sh[3][e]) * (1.f / NTOK);
      float d = load - 0.125f;
      aux += d * d;
    }
    out_aux[0] = aux;
  }
}

// ------- scatter: expert row lists + per-token assignment rows (into topi) -------
__global__ __launch_bounds__(256) void scatter_kernel(
    int* __restrict__ topi, const float* __restrict__ topp,
    unsigned* cursors, int* row_token, float* row_p) {
  int tok = blockIdx.x * 256 + threadIdx.x;
  if (tok >= NTOK) return;
#pragma unroll
  for (int k = 0; k < 2; ++k) {
    int e = topi[tok * 2 + k];
    unsigned pos = atomicAdd(&cursors[e], 1u);
    row_token[pos] = tok;
    row_p[pos] = topp[tok * 2 + k];
    topi[tok * 2 + k] = (int)pos;   // inverse map for combine
  }
}

// ---------------- combine: out = x + y[kh0..1][r0] + y[kh0..1][r1] ----------------
__global__ __launch_bounds__(256) void combine_kernel(
    const float* __restrict__ x, const unsigned short* __restrict__ y,
    const int* __restrict__ asn, float* __restrict__ out) {
  const int tok = blockIdx.x;
  const int t = threadIdx.x;
  const int r0 = asn[tok * 2], r1 = asn[tok * 2 + 1];
  float4 xv = *(const float4*)(x + (size_t)tok * DM + t * 4);
  const size_t HALF = (size_t)16384 * DM;
  ushort4 a0 = *(const ushort4*)(y + (size_t)r0 * DM + t * 4);
  ushort4 a1 = *(const ushort4*)(y + HALF + (size_t)r0 * DM + t * 4);
  ushort4 b0 = *(const ushort4*)(y + (size_t)r1 * DM + t * 4);
  ushort4 b1 = *(const ushort4*)(y + HALF + (size_t)r1 * DM + t * 4);
  float4 o;
  o.x = xv.x + bf2f(a0.x) + bf2f(a1.x) + bf2f(b0.x) + bf2f(b1.x);
  o.y = xv.y + bf2f(a0.y) + bf2f(a1.y) + bf2f(b0.y) + bf2f(b1.y);
  o.z = xv.z + bf2f(a0.z) + bf2f(a1.z) + bf2f(b0.z) + bf2f(b1.z);
  o.w = xv.w + bf2f(a0.w) + bf2f(a1.w) + bf2f(b0.w) + bf2f(b1.w);
  *(float4*)(out + (size_t)tok * DM + t * 4) = o;
}

// =====================================================================
// m97-structure GEMMs (UNCHANGED from R8/R9): 128x128 tile, BK=64,
// 4 waves, single 32 KB LDS, 2 barriers per K-step, 32 MFMA per barrier.
// ONE item per block; 2D supertile order sized to the 4 MB per-XCD L2.
// =====================================================================

// ---------------- GEMM1: h = silu(xn[gather] @ w1 + b1) ----------------
__global__ __launch_bounds__(256, 4) void gemm1_kernel(
    const unsigned short* __restrict__ xnb,
    const unsigned short* __restrict__ w1t,
    const float* __restrict__ b1,
    const int* __restrict__ row_token,
    unsigned short* __restrict__ h,
    const int4* __restrict__ tiles, const int* __restrict__ ntiles_p) {
  const int ntiles = *ntiles_p;
  int s_, e_;
  chunk_range(((ntiles + 7) >> 3) << 8, &s_, &e_);
  if (s_ >= e_) return;
  const int w = s_;
  const int tile = ((w >> 8) << 3) + ((w >> 3) & 7);
  if (tile >= ntiles) return;
  const int n0 = ((((w >> 6) & 3) << 3) + (w & 7)) << 7;

  __shared__ unsigned short As[128 * 64];
  __shared__ unsigned short Bs[128 * 64];
  const int t = threadIdx.x, lane = t & 63, wave = t >> 6;
  const int wr = wave >> 1, wc = wave & 1;
  const int swz = ((t & 7) ^ ((t >> 3) & 7)) * 8;

  const int4 td = tiles[tile];
  const int e = td.x, row_start = td.y, nrows = td.z;
  const unsigned short* Bw = w1t + (size_t)e * ((size_t)DF * DM);

  const unsigned short* asrc[4];
  const unsigned short* bsrc[4];
#pragma unroll
  for (int it = 0; it < 4; ++it) {
    int r = it * 32 + (t >> 3);
    int rc = r < nrows ? r : (nrows - 1);
    asrc[it] = xnb + (size_t)row_token[row_start + rc] * DM + swz;
    bsrc[it] = Bw + (size_t)(n0 + r) * DM + swz;
  }
  f32x4 acc[4][4];
#pragma unroll
  for (int i = 0; i < 4; ++i)
#pragma unroll
    for (int j = 0; j < 4; ++j) acc[i][j] = (f32x4){0.f, 0.f, 0.f, 0.f};

  for (int kt = 0; kt < DM / 64; ++kt) {
    const int k0 = kt * 64;
#pragma unroll
    for (int it = 0; it < 4; ++it) {
      gload_lds16(asrc[it] + k0, &As[it * 2048 + wave * 512]);
      gload_lds16(bsrc[it] + k0, &Bs[it * 2048 + wave * 512]);
    }
    __syncthreads();
#pragma unroll
    for (int ks = 0; ks < 2; ++ks) {
      const int slot = ((ks * 4 + (lane >> 4)) ^ (lane & 7)) * 8;
      s16x8 af[4], bfr[4];
#pragma unroll
      for (int mf = 0; mf < 4; ++mf)
        af[mf] = *(const s16x8*)&As[(wr * 64 + mf * 16 + (lane & 15)) * 64 + slot];
#pragma unroll
      for (int nf = 0; nf < 4; ++nf)
        bfr[nf] = *(const s16x8*)&Bs[(wc * 64 + nf * 16 + (lane & 15)) * 64 + slot];
#pragma unroll
      for (int mf = 0; mf < 4; ++mf)
#pragma unroll
        for (int nf = 0; nf < 4; ++nf)
          acc[mf][nf] = __builtin_amdgcn_mfma_f32_16x16x32_bf16(af[mf], bfr[nf],
                                                                acc[mf][nf], 0, 0, 0);
    }
    __syncthreads();
  }

  const float* b1e = b1 + e * DF;
#pragma unroll
  for (int mf = 0; mf < 4; ++mf) {
    int rbase = wr * 64 + mf * 16 + ((lane >> 4) << 2);
#pragma unroll
    for (int nf = 0; nf < 4; ++nf) {
      int col = n0 + wc * 64 + nf * 16 + (lane & 15);
      float bias = b1e[col];
#pragma unroll
      for (int r = 0; r < 4; ++r) {
        int rl = rbase + r;
        if (rl < nrows) {
          float v = acc[mf][nf][r] + bias;
          float sv = v / (1.f + __expf(-v));
          h[(size_t)(row_start + rl) * DF + col] = f2bf(sv);
        }
      }
    }
  }
}

// ------- GEMM2: y[kh][row] = p*(h @ w2[,kh] + (kh==0)*b2), 128x128, K-split 2 -------
__global__ __launch_bounds__(256, 4) void gemm2_kernel(
    const unsigned short* __restrict__ h,
    const unsigned short* __restrict__ w2t,
    const float* __restrict__ b2,
    const float* __restrict__ row_p,
    const int4* __restrict__ tiles, const int* __restrict__ ntiles_p,
    unsigned short* __restrict__ y) {
  const int ntiles = *ntiles_p;
  int s_, e_;
  chunk_range(((ntiles + 3) >> 2) << 6, &s_, &e_);
  if (s_ >= e_) return;
  const int w = s_;
  const int tile = ((w >> 6) << 2) + ((w >> 2) & 3);
  if (tile >= ntiles) return;
  const int kh = (w >> 5) & 1;
  const int n0 = ((((w >> 4) & 1) << 2) + (w & 3)) << 7;

  __shared__ unsigned short As[128 * 64];
  __shared__ unsigned short Bs[128 * 64];
  const int t = threadIdx.x, lane = t & 63, wave = t >> 6;
  const int wr = wave >> 1, wc = wave & 1;
  const int swz = ((t & 7) ^ ((t >> 3) & 7)) * 8;

  const int4 td = tiles[tile];
  const int e = td.x, row_start = td.y, nrows = td.z;
  const unsigned short* Bw = w2t + (size_t)e * ((size_t)DM * DF);

  const unsigned short* asrc[4];
  const unsigned short* bsrc[4];
#pragma unroll
  for (int it = 0; it < 4; ++it) {
    int r = it * 32 + (t >> 3);
    int rc = r < nrows ? r : (nrows - 1);
    asrc[it] = h + (size_t)(row_start + rc) * DF + swz;
    bsrc[it] = Bw + (size_t)(n0 + r) * DF + swz;
  }
  f32x4 acc[4][4];
#pragma unroll
  for (int i = 0; i < 4; ++i)
#pragma unroll
    for (int j = 0; j < 4; ++j) acc[i][j] = (f32x4){0.f, 0.f, 0.f, 0.f};

  const int ktEnd = kh * 32 + 32;
  for (int kt = kh * 32; kt < ktEnd; ++kt) {
    const int k0 = kt * 64;
#pragma unroll
    for (int it = 0; it < 4; ++it) {
      gload_lds16(asrc[it] + k0, &As[it * 2048 + wave * 512]);
      gload_lds16(bsrc[it] + k0, &Bs[it * 2048 + wave * 512]);
    }
    __syncthreads();
#pragma unroll
    for (int ks = 0; ks < 2; ++ks) {
      const int slot = ((ks * 4 + (lane >> 4)) ^ (lane & 7)) * 8;
      s16x8 af[4], bfr[4];
#pragma unroll
      for (int mf = 0; mf < 4; ++mf)
        af[mf] = *(const s16x8*)&As[(wr * 64 + mf * 16 + (lane & 15)) * 64 + slot];
#pragma unroll
      for (int nf = 0; nf < 4; ++nf)
        bfr[nf] = *(const s16x8*)&Bs[(wc * 64 + nf * 16 + (lane & 15)) * 64 + slot];
#pragma unroll
      for (int mf = 0; mf < 4; ++mf)
#pragma unroll
        for (int nf = 0; nf < 4; ++nf)
          acc[mf][nf] = __builtin_amdgcn_mfma_f32_16x16x32_bf16(af[mf], bfr[nf],
                                                                acc[mf][nf], 0, 0, 0);
    }
    __syncthreads();
  }

  const float* b2e = b2 + e * DM;
  unsigned short* yk = y + (size_t)kh * ((size_t)16384 * DM);
#pragma unroll
  for (int mf = 0; mf < 4; ++mf) {
    int rbase = wr * 64 + mf * 16 + ((lane >> 4) << 2);
    float prr[4]; int rok[4];
#pragma unroll
    for (int r = 0; r < 4; ++r) {
      int rl = rbase + r;
      rok[r] = rl < nrows;
      prr[r] = rok[r] ? row_p[row_start + rl] : 0.f;
    }
#pragma unroll
    for (int nf = 0; nf < 4; ++nf) {
      int col = n0 + wc * 64 + nf * 16 + (lane & 15);
      float bias = kh == 0 ? b2e[col] : 0.f;
#pragma unroll
      for (int r = 0; r < 4; ++r) {
        if (rok[r]) {
          float v = prr[r] * (acc[mf][nf][r] + bias);
          yk[(size_t)(row_start + rbase + r) * DM + col] = f2bf(v);
        }
      }
    }
  }
}

// ---------------- launch ----------------
extern "C" void kernel_launch(void* const* d_in, const int* in_sizes, int n_in,
                              void* d_out, int out_size, void* d_ws, size_t ws_size,
                              hipStream_t stream) {
  const float* x     = (const float*)d_in[0];
  const float* gamma = (const float*)d_in[1];
  const float* beta  = (const float*)d_in[2];
  const float* rw    = (const float*)d_in[3];
  const float* rb    = (const float*)d_in[4];
  const float* w1    = (const float*)d_in[5];
  const float* b1    = (const float*)d_in[6];
  const float* w2    = (const float*)d_in[7];
  const float* b2    = (const float*)d_in[8];
  float* out = (float*)d_out;
  char* ws = (char*)d_ws;

  if (ws_size < WS_NEEDED) {
    sentinel_kernel<<<2048, 256, 0, stream>>>(out, out_size);
    return;
  }

  unsigned short* xnb = (unsigned short*)(ws + OFF_XN);
  unsigned short* w1t = (unsigned short*)(ws + OFF_W1T);
  unsigned short* y   = (unsigned short*)(ws + OFF_W1T);  // overlays w1t after gemm1
  unsigned short* w2t = (unsigned short*)(ws + OFF_W2T);
  unsigned short* h   = (unsigned short*)(ws + OFF_H);
  float* probs        = (float*)(ws + OFF_PROBS);
  int* topi           = (int*)(ws + OFF_TOPI);
  float* topp         = (float*)(ws + OFF_TOPP);
  int* row_token      = (int*)(ws + OFF_ROWTOK);
  float* row_p        = (float*)(ws + OFF_ROWP);
  unsigned* counts    = (unsigned*)(ws + OFF_COUNTS);
  unsigned* cursors   = (unsigned*)(ws + OFF_CURSORS);
  int* ntiles         = (int*)(ws + OFF_NTILES);
  int4* tiles         = (int4*)(ws + OFF_TILES);

  init_kernel<<<1, 64, 0, stream>>>(counts);
  front_kernel<<<16384, 256, 0, stream>>>(x, gamma, beta, rw, rb, xnb, probs,
                                          topi, topp, counts, w1, w1t, w2, w2t);
  plan_aux_kernel<<<1, 256, 0, stream>>>(counts, cursors, tiles, ntiles, probs,
                                         out + (size_t)NTOK * DM);
  scatter_kernel<<<NTOK / 256, 256, 0, stream>>>(topi, topp, cursors, row_token, row_p);
  // max items: gemm1 = ceil(136/8)*256 = 4352; gemm2 = ceil(136/4)*64 = 2176
  gemm1_kernel<<<4352, 256, 0, stream>>>(xnb, w1t, b1, row_token, h, tiles, ntiles);
  gemm2_kernel<<<2176, 256, 0, stream>>>(h, w2t, b2, row_p, tiles, ntiles, y);
  combine_kernel<<<NTOK, 256, 0, stream>>>(x, y, topi, out);
}

// Round 12
// 699.332 us; speedup vs baseline: 1.0306x; 1.0306x over previous
//
#include <hip/hip_runtime.h>
#include <math.h>

#define NTOK 8192
#define DM 1024
#define NE 8
#define DF 4096
#define MAXTILES 136   // 128-row tiles: <=128 full + <=8 partial

typedef short  s16x8 __attribute__((ext_vector_type(8)));
typedef float  f32x4 __attribute__((ext_vector_type(4)));

// ---------------- workspace layout (bytes) ----------------
#define OFF_XN      0ull                       // 8192*1024*2        = 16777216
#define OFF_W1T     16777216ull                // 8*4096*1024*2      = 67108864  (y overlays after gemm1)
#define OFF_W2T     83886080ull                // 8*1024*4096*2      = 67108864
#define OFF_H       150994944ull               // 16384*4096*2       = 134217728
#define OFF_PROBS   285212672ull               // 8192*8*4           = 262144
#define OFF_TOPI    285474816ull               // 8192*2*4           = 65536 (becomes asn rows)
#define OFF_TOPP    285540352ull               // 8192*2*4           = 65536
#define OFF_ROWTOK  285605888ull               // 16384*4            = 65536
#define OFF_ROWP    285671424ull               // 16384*4            = 65536
#define OFF_COUNTS  285736960ull               // 8*4
#define OFF_CURSORS 285736992ull               // 8*4
#define OFF_NTILES  285737024ull               // 4 (+pad)
#define OFF_TILES   285737088ull               // 136*16 = 2176
#define WS_NEEDED   285739264ull

__device__ __forceinline__ unsigned short f2bf(float f) {
  unsigned u = __builtin_bit_cast(unsigned, f);
  u += 0x7fffu + ((u >> 16) & 1u);
  return (unsigned short)(u >> 16);
}
__device__ __forceinline__ float bf2f(unsigned short s) {
  unsigned u = ((unsigned)s) << 16;
  return __builtin_bit_cast(float, u);
}

__device__ __forceinline__ void gload_lds16(const void* g, void* l) {
  __builtin_amdgcn_global_load_lds(
      (const __attribute__((address_space(1))) void*)g,
      (__attribute__((address_space(3))) void*)l, 16, 0, 0);
}

// XCD-aware CHUNKED item range (one item per block when grid >= nItems).
__device__ __forceinline__ void chunk_range(int nItems, int* s, int* e) {
  const int xcd = blockIdx.x & 7, lnx = blockIdx.x >> 3;
  const int nbx = (int)(gridDim.x >> 3);
  const int cs = nItems >> 3, cr = nItems & 7;
  const int base = xcd * cs + (xcd < cr ? xcd : cr);
  const int csz  = cs + (xcd < cr ? 1 : 0);
  const int q = csz / nbx, r = csz % nbx;
  *s = base + lnx * q + (lnx < r ? lnx : r);
  *e = *s + q + (lnx < r ? 1 : 0);
}

// ---------------- init: zero expert counts ----------------
__global__ void init_kernel(unsigned* counts) {
  if (threadIdx.x < NE) counts[threadIdx.x] = 0u;
}

// ---------------- sentinel if ws too small ----------------
__global__ void sentinel_kernel(float* out, int n) {
  for (int i = blockIdx.x * 256 + threadIdx.x; i < n; i += 2048 * 256)
    out[i] = -12345.0f;
}

// ---------------- shared transpose-cast tile body (R9-verified) ----------------
__device__ __forceinline__ void transpose_tile(
    const float* __restrict__ w, unsigned short* __restrict__ wt,
    int R, int C, int tau, int t, float (*tile)[65]) {
  const int e = tau >> 10;
  const int rem = tau & 1023;
  const int nbc = C >> 6;                 // col-tiles per expert
  const int c0 = (rem % nbc) << 6;
  const int r0 = (rem / nbc) << 6;
  const float* we = w + (size_t)e * R * C;
  unsigned short* wte = wt + (size_t)e * R * C;
  const int rr = t >> 4, cc = (t & 15) * 4;
#pragma unroll
  for (int i = 0; i < 4; ++i) {
    float4 v = *(const float4*)(we + (size_t)(r0 + rr + i * 16) * C + c0 + cc);
    tile[rr + i * 16][cc]     = v.x;
    tile[rr + i * 16][cc + 1] = v.y;
    tile[rr + i * 16][cc + 2] = v.z;
    tile[rr + i * 16][cc + 3] = v.w;
  }
  __syncthreads();
  const int col = t >> 4, r4 = (t & 15) * 4;
#pragma unroll
  for (int i = 0; i < 4; ++i) {
    int c = col + i * 16;
    ushort4 o;
    o.x = f2bf(tile[r4][c]);     o.y = f2bf(tile[r4 + 1][c]);
    o.z = f2bf(tile[r4 + 2][c]); o.w = f2bf(tile[r4 + 3][c]);
    *(ushort4*)(wte + (size_t)(c0 + c) * R + r0 + r4) = o;
  }
}

// =====================================================================
// front_kernel: heterogeneous launch:
//   bid <  8192          : w1 transpose-cast tile (tau = bid)
//   8192 <= bid < 16384  : LayerNorm + router for token (bid-8192)
// (w2 transpose is fused into the gemm1 launch -- w2t is only needed by
//  gemm2, so it runs concurrently with gemm1 in gemm1's CU/BW slack.)
// =====================================================================
__global__ __launch_bounds__(256) void front_kernel(
    const float* __restrict__ x, const float* __restrict__ gamma,
    const float* __restrict__ beta, const float* __restrict__ rw,
    const float* __restrict__ rb, unsigned short* __restrict__ xnb,
    float* __restrict__ probs, int* __restrict__ topi,
    float* __restrict__ topp, unsigned* __restrict__ counts,
    const float* __restrict__ w1, unsigned short* __restrict__ w1t) {
  __shared__ float tile[64][65];
  const int bid = blockIdx.x;
  const int t = threadIdx.x;

  if (bid < 8192) {
    transpose_tile(w1, w1t, DM, DF, bid, t, tile);
    return;
  }

  // ---------------- LayerNorm + router ----------------
  const int tok = bid - 8192;
  const int lane = t & 63, wave = t >> 6;
  float* red  = &tile[0][0];    // 16 floats
  float* lred = &tile[1][0];    // 32 floats

  float4 xv = *(const float4*)(x + (size_t)tok * DM + t * 4);
  float s = xv.x + xv.y + xv.z + xv.w;
  float q = xv.x * xv.x + xv.y * xv.y + xv.z * xv.z + xv.w * xv.w;
  for (int o = 32; o > 0; o >>= 1) {
    s += __shfl_down(s, o);
    q += __shfl_down(q, o);
  }
  if (lane == 0) { red[wave] = s; red[8 + wave] = q; }
  __syncthreads();
  float tot  = red[0] + red[1] + red[2] + red[3];
  float totq = red[8] + red[9] + red[10] + red[11];
  float mu = tot * (1.0f / DM);
  float var = totq * (1.0f / DM) - mu * mu;
  float rstd = rsqrtf(var + 1e-5f);

  float4 g = *(const float4*)(gamma + t * 4);
  float4 b = *(const float4*)(beta + t * 4);
  float xn[4];
  xn[0] = (xv.x - mu) * rstd * g.x + b.x;
  xn[1] = (xv.y - mu) * rstd * g.y + b.y;
  xn[2] = (xv.z - mu) * rstd * g.z + b.z;
  xn[3] = (xv.w - mu) * rstd * g.w + b.w;
  ushort4 pk = { f2bf(xn[0]), f2bf(xn[1]), f2bf(xn[2]), f2bf(xn[3]) };
  *(ushort4*)(xnb + (size_t)tok * DM + t * 4) = pk;

  float a[8] = {0, 0, 0, 0, 0, 0, 0, 0};
  const float4* r4 = (const float4*)(rw + (size_t)t * 32);
#pragma unroll
  for (int j = 0; j < 4; ++j) {
    float4 lo = r4[j * 2], hi = r4[j * 2 + 1];
    a[0] += xn[j] * lo.x; a[1] += xn[j] * lo.y;
    a[2] += xn[j] * lo.z; a[3] += xn[j] * lo.w;
    a[4] += xn[j] * hi.x; a[5] += xn[j] * hi.y;
    a[6] += xn[j] * hi.z; a[7] += xn[j] * hi.w;
  }
#pragma unroll
  for (int e = 0; e < 8; ++e)
    for (int o = 32; o > 0; o >>= 1) a[e] += __shfl_down(a[e], o);
  if (lane == 0) {
#pragma unroll
    for (int e = 0; e < 8; ++e) lred[wave * 8 + e] = a[e];
  }
  __syncthreads();
  if (t == 0) {
    float lg[8], mx = -1e30f;
#pragma unroll
    for (int e = 0; e < 8; ++e) {
      lg[e] = lred[e] + lred[8 + e] + lred[16 + e] + lred[24 + e] + rb[e];
      mx = fmaxf(mx, lg[e]);
    }
    float ex[8], se = 0.f;
#pragma unroll
    for (int e = 0; e < 8; ++e) { ex[e] = expf(lg[e] - mx); se += ex[e]; }
    float inv = 1.f / se;
    float pr[8];
#pragma unroll
    for (int e = 0; e < 8; ++e) {
      pr[e] = ex[e] * inv;
      probs[tok * 8 + e] = pr[e];
    }
    int i0 = 0;
#pragma unroll
    for (int e = 1; e < 8; ++e) if (pr[e] > pr[i0]) i0 = e;
    int i1 = (i0 == 0) ? 1 : 0;
#pragma unroll
    for (int e = 0; e < 8; ++e)
      if (e != i0 && pr[e] > pr[i1]) i1 = e;
    float p0 = pr[i0], p1 = pr[i1], inv2 = 1.f / (p0 + p1);
    topi[tok * 2] = i0; topi[tok * 2 + 1] = i1;
    topp[tok * 2] = p0 * inv2; topp[tok * 2 + 1] = p1 * inv2;
    atomicAdd(&counts[i0], 1u);
    atomicAdd(&counts[i1], 1u);
  }
}

// ------- plan (t0) + aux loss (all threads), one 256-thread block -------
__global__ __launch_bounds__(256) void plan_aux_kernel(
    const unsigned* __restrict__ counts, unsigned* __restrict__ cursors,
    int4* __restrict__ tiles, int* __restrict__ ntiles,
    const float* __restrict__ probs, float* __restrict__ out_aux) {
  const int t = threadIdx.x;
  if (t == 0) {
    unsigned o = 0; int nt = 0;
    for (int e = 0; e < NE; ++e) {
      cursors[e] = o;
      unsigned c = counts[e];
      for (unsigned st = 0; st < c; st += 128u) {
        unsigned nr = c - st; if (nr > 128u) nr = 128u;
        tiles[nt] = make_int4(e, (int)(o + st), (int)nr, 0);
        ++nt;
      }
      o += c;
    }
    *ntiles = nt;
  }
  float a[8] = {0, 0, 0, 0, 0, 0, 0, 0};
  for (int tok = t; tok < NTOK; tok += 256) {
    const float4* p4 = (const float4*)(probs + (size_t)tok * 8);
    float4 lo = p4[0], hi = p4[1];
    a[0] += lo.x; a[1] += lo.y; a[2] += lo.z; a[3] += lo.w;
    a[4] += hi.x; a[5] += hi.y; a[6] += hi.z; a[7] += hi.w;
  }
  const int lane = t & 63, wave = t >> 6;
#pragma unroll
  for (int e = 0; e < 8; ++e)
    for (int o = 32; o > 0; o >>= 1) a[e] += __shfl_down(a[e], o);
  __shared__ float sh[4][8];
  if (lane == 0) {
#pragma unroll
    for (int e = 0; e < 8; ++e) sh[wave][e] = a[e];
  }
  __syncthreads();
  if (t == 0) {
    float aux = 0.f;
#pragma unroll
    for (int e = 0; e < 8; ++e) {
      float load = (sh[0][e] + sh[1][e] + sh[2][e] + sh[3][e]) * (1.f / NTOK);
      float d = load - 0.125f;
      aux += d * d;
    }
    out_aux[0] = aux;
  }
}

// ------- scatter: expert row lists + per-token assignment rows (into topi) -------
__global__ __launch_bounds__(256) void scatter_kernel(
    int* __restrict__ topi, const float* __restrict__ topp,
    unsigned* cursors, int* row_token, float* row_p) {
  int tok = blockIdx.x * 256 + threadIdx.x;
  if (tok >= NTOK) return;
#pragma unroll
  for (int k = 0; k < 2; ++k) {
    int e = topi[tok * 2 + k];
    unsigned pos = atomicAdd(&cursors[e], 1u);
    row_token[pos] = tok;
    row_p[pos] = topp[tok * 2 + k];
    topi[tok * 2 + k] = (int)pos;   // inverse map for combine
  }
}

// ---------------- combine: out = x + y[kh0..1][r0] + y[kh0..1][r1] ----------------
__global__ __launch_bounds__(256) void combine_kernel(
    const float* __restrict__ x, const unsigned short* __restrict__ y,
    const int* __restrict__ asn, float* __restrict__ out) {
  const int tok = blockIdx.x;
  const int t = threadIdx.x;
  const int r0 = asn[tok * 2], r1 = asn[tok * 2 + 1];
  float4 xv = *(const float4*)(x + (size_t)tok * DM + t * 4);
  const size_t HALF = (size_t)16384 * DM;
  ushort4 a0 = *(const ushort4*)(y + (size_t)r0 * DM + t * 4);
  ushort4 a1 = *(const ushort4*)(y + HALF + (size_t)r0 * DM + t * 4);
  ushort4 b0 = *(const ushort4*)(y + (size_t)r1 * DM + t * 4);
  ushort4 b1 = *(const ushort4*)(y + HALF + (size_t)r1 * DM + t * 4);
  float4 o;
  o.x = xv.x + bf2f(a0.x) + bf2f(a1.x) + bf2f(b0.x) + bf2f(b1.x);
  o.y = xv.y + bf2f(a0.y) + bf2f(a1.y) + bf2f(b0.y) + bf2f(b1.y);
  o.z = xv.z + bf2f(a0.z) + bf2f(a1.z) + bf2f(b0.z) + bf2f(b1.z);
  o.w = xv.w + bf2f(a0.w) + bf2f(a1.w) + bf2f(b0.w) + bf2f(b1.w);
  *(float4*)(out + (size_t)tok * DM + t * 4) = o;
}

// =====================================================================
// m97-structure GEMMs (inner loop identical to R8/R9): 128x128 tile,
// BK=64, 4 waves, single 32 KB LDS, 2 barriers per K-step, 32 MFMA per
// barrier. ONE item per block; supertile order sized to 4 MB L2.
// gemm1 launch additionally carries 8192 w2-transpose blocks (bid>=4352)
// that run in gemm1's CU/BW slack; gemm2 (later in stream) sees w2t done.
// =====================================================================

#define GEMM1_BLOCKS 4352   // ceil(MAXTILES/8)*256

// ---------------- GEMM1: h = silu(xn[gather] @ w1 + b1)  (+ fused w2T) ----------------
__global__ __launch_bounds__(256, 4) void gemm1_kernel(
    const unsigned short* __restrict__ xnb,
    const unsigned short* __restrict__ w1t,
    const float* __restrict__ b1,
    const int* __restrict__ row_token,
    unsigned short* __restrict__ h,
    const int4* __restrict__ tiles, const int* __restrict__ ntiles_p,
    const float* __restrict__ w2, unsigned short* __restrict__ w2t) {
  __shared__ char smem[32768];
  const int t = threadIdx.x;

  if (blockIdx.x >= GEMM1_BLOCKS) {
    // -------- fused w2 transpose-cast tile --------
    float (*tile)[65] = (float(*)[65])smem;
    transpose_tile(w2, w2t, DF, DM, (int)blockIdx.x - GEMM1_BLOCKS, t, tile);
    return;
  }

  unsigned short* As = (unsigned short*)smem;
  unsigned short* Bs = (unsigned short*)(smem + 16384);

  const int ntiles = *ntiles_p;
  // explicit item map with nbx = GEMM1_BLOCKS/8 (grid carries extra blocks)
  const int nItems = ((ntiles + 7) >> 3) << 8;
  const int xcd = blockIdx.x & 7, lnx = blockIdx.x >> 3;
  const int cs = nItems >> 3, cr = nItems & 7;
  const int base = xcd * cs + (xcd < cr ? xcd : cr);
  const int csz  = cs + (xcd < cr ? 1 : 0);
  const int q = csz / (GEMM1_BLOCKS / 8), r = csz % (GEMM1_BLOCKS / 8);
  const int s_ = base + lnx * q + (lnx < r ? lnx : r);
  const int e_ = s_ + q + (lnx < r ? 1 : 0);
  if (s_ >= e_) return;
  const int w = s_;
  const int tile = ((w >> 8) << 3) + ((w >> 3) & 7);
  if (tile >= ntiles) return;
  const int n0 = ((((w >> 6) & 3) << 3) + (w & 7)) << 7;

  const int lane = t & 63, wave = t >> 6;
  const int wr = wave >> 1, wc = wave & 1;
  const int swz = ((t & 7) ^ ((t >> 3) & 7)) * 8;

  const int4 td = tiles[tile];
  const int e = td.x, row_start = td.y, nrows = td.z;
  const unsigned short* Bw = w1t + (size_t)e * ((size_t)DF * DM);

  const unsigned short* asrc[4];
  const unsigned short* bsrc[4];
#pragma unroll
  for (int it = 0; it < 4; ++it) {
    int rr = it * 32 + (t >> 3);
    int rc = rr < nrows ? rr : (nrows - 1);
    asrc[it] = xnb + (size_t)row_token[row_start + rc] * DM + swz;
    bsrc[it] = Bw + (size_t)(n0 + rr) * DM + swz;
  }
  f32x4 acc[4][4];
#pragma unroll
  for (int i = 0; i < 4; ++i)
#pragma unroll
    for (int j = 0; j < 4; ++j) acc[i][j] = (f32x4){0.f, 0.f, 0.f, 0.f};

  for (int kt = 0; kt < DM / 64; ++kt) {
    const int k0 = kt * 64;
#pragma unroll
    for (int it = 0; it < 4; ++it) {
      gload_lds16(asrc[it] + k0, &As[it * 2048 + wave * 512]);
      gload_lds16(bsrc[it] + k0, &Bs[it * 2048 + wave * 512]);
    }
    __syncthreads();
#pragma unroll
    for (int ks = 0; ks < 2; ++ks) {
      const int slot = ((ks * 4 + (lane >> 4)) ^ (lane & 7)) * 8;
      s16x8 af[4], bfr[4];
#pragma unroll
      for (int mf = 0; mf < 4; ++mf)
        af[mf] = *(const s16x8*)&As[(wr * 64 + mf * 16 + (lane & 15)) * 64 + slot];
#pragma unroll
      for (int nf = 0; nf < 4; ++nf)
        bfr[nf] = *(const s16x8*)&Bs[(wc * 64 + nf * 16 + (lane & 15)) * 64 + slot];
#pragma unroll
      for (int mf = 0; mf < 4; ++mf)
#pragma unroll
        for (int nf = 0; nf < 4; ++nf)
          acc[mf][nf] = __builtin_amdgcn_mfma_f32_16x16x32_bf16(af[mf], bfr[nf],
                                                                acc[mf][nf], 0, 0, 0);
    }
    __syncthreads();
  }

  const float* b1e = b1 + e * DF;
#pragma unroll
  for (int mf = 0; mf < 4; ++mf) {
    int rbase = wr * 64 + mf * 16 + ((lane >> 4) << 2);
#pragma unroll
    for (int nf = 0; nf < 4; ++nf) {
      int col = n0 + wc * 64 + nf * 16 + (lane & 15);
      float bias = b1e[col];
#pragma unroll
      for (int rr = 0; rr < 4; ++rr) {
        int rl = rbase + rr;
        if (rl < nrows) {
          float v = acc[mf][nf][rr] + bias;
          float sv = v / (1.f + __expf(-v));
          h[(size_t)(row_start + rl) * DF + col] = f2bf(sv);
        }
      }
    }
  }
}

// ------- GEMM2: y[kh][row] = p*(h @ w2[,kh] + (kh==0)*b2), 128x128, K-split 2 -------
__global__ __launch_bounds__(256, 4) void gemm2_kernel(
    const unsigned short* __restrict__ h,
    const unsigned short* __restrict__ w2t,
    const float* __restrict__ b2,
    const float* __restrict__ row_p,
    const int4* __restrict__ tiles, const int* __restrict__ ntiles_p,
    unsigned short* __restrict__ y) {
  const int ntiles = *ntiles_p;
  int s_, e_;
  chunk_range(((ntiles + 3) >> 2) << 6, &s_, &e_);
  if (s_ >= e_) return;
  const int w = s_;
  const int tile = ((w >> 6) << 2) + ((w >> 2) & 3);
  if (tile >= ntiles) return;
  const int kh = (w >> 5) & 1;
  const int n0 = ((((w >> 4) & 1) << 2) + (w & 3)) << 7;

  __shared__ unsigned short As[128 * 64];
  __shared__ unsigned short Bs[128 * 64];
  const int t = threadIdx.x, lane = t & 63, wave = t >> 6;
  const int wr = wave >> 1, wc = wave & 1;
  const int swz = ((t & 7) ^ ((t >> 3) & 7)) * 8;

  const int4 td = tiles[tile];
  const int e = td.x, row_start = td.y, nrows = td.z;
  const unsigned short* Bw = w2t + (size_t)e * ((size_t)DM * DF);

  const unsigned short* asrc[4];
  const unsigned short* bsrc[4];
#pragma unroll
  for (int it = 0; it < 4; ++it) {
    int rr = it * 32 + (t >> 3);
    int rc = rr < nrows ? rr : (nrows - 1);
    asrc[it] = h + (size_t)(row_start + rc) * DF + swz;
    bsrc[it] = Bw + (size_t)(n0 + rr) * DF + swz;
  }
  f32x4 acc[4][4];
#pragma unroll
  for (int i = 0; i < 4; ++i)
#pragma unroll
    for (int j = 0; j < 4; ++j) acc[i][j] = (f32x4){0.f, 0.f, 0.f, 0.f};

  const int ktEnd = kh * 32 + 32;
  for (int kt = kh * 32; kt < ktEnd; ++kt) {
    const int k0 = kt * 64;
#pragma unroll
    for (int it = 0; it < 4; ++it) {
      gload_lds16(asrc[it] + k0, &As[it * 2048 + wave * 512]);
      gload_lds16(bsrc[it] + k0, &Bs[it * 2048 + wave * 512]);
    }
    __syncthreads();
#pragma unroll
    for (int ks = 0; ks < 2; ++ks) {
      const int slot = ((ks * 4 + (lane >> 4)) ^ (lane & 7)) * 8;
      s16x8 af[4], bfr[4];
#pragma unroll
      for (int mf = 0; mf < 4; ++mf)
        af[mf] = *(const s16x8*)&As[(wr * 64 + mf * 16 + (lane & 15)) * 64 + slot];
#pragma unroll
      for (int nf = 0; nf < 4; ++nf)
        bfr[nf] = *(const s16x8*)&Bs[(wc * 64 + nf * 16 + (lane & 15)) * 64 + slot];
#pragma unroll
      for (int mf = 0; mf < 4; ++mf)
#pragma unroll
        for (int nf = 0; nf < 4; ++nf)
          acc[mf][nf] = __builtin_amdgcn_mfma_f32_16x16x32_bf16(af[mf], bfr[nf],
                                                                acc[mf][nf], 0, 0, 0);
    }
    __syncthreads();
  }

  const float* b2e = b2 + e * DM;
  unsigned short* yk = y + (size_t)kh * ((size_t)16384 * DM);
#pragma unroll
  for (int mf = 0; mf < 4; ++mf) {
    int rbase = wr * 64 + mf * 16 + ((lane >> 4) << 2);
    float prr[4]; int rok[4];
#pragma unroll
    for (int rr = 0; rr < 4; ++rr) {
      int rl = rbase + rr;
      rok[rr] = rl < nrows;
      prr[rr] = rok[rr] ? row_p[row_start + rl] : 0.f;
    }
#pragma unroll
    for (int nf = 0; nf < 4; ++nf) {
      int col = n0 + wc * 64 + nf * 16 + (lane & 15);
      float bias = kh == 0 ? b2e[col] : 0.f;
#pragma unroll
      for (int rr = 0; rr < 4; ++rr) {
        if (rok[rr]) {
          float v = prr[rr] * (acc[mf][nf][rr] + bias);
          yk[(size_t)(row_start + rbase + rr) * DM + col] = f2bf(v);
        }
      }
    }
  }
}

// ---------------- launch ----------------
extern "C" void kernel_launch(void* const* d_in, const int* in_sizes, int n_in,
                              void* d_out, int out_size, void* d_ws, size_t ws_size,
                              hipStream_t stream) {
  const float* x     = (const float*)d_in[0];
  const float* gamma = (const float*)d_in[1];
  const float* beta  = (const float*)d_in[2];
  const float* rw    = (const float*)d_in[3];
  const float* rb    = (const float*)d_in[4];
  const float* w1    = (const float*)d_in[5];
  const float* b1    = (const float*)d_in[6];
  const float* w2    = (const float*)d_in[7];
  const float* b2    = (const float*)d_in[8];
  float* out = (float*)d_out;
  char* ws = (char*)d_ws;

  if (ws_size < WS_NEEDED) {
    sentinel_kernel<<<2048, 256, 0, stream>>>(out, out_size);
    return;
  }

  unsigned short* xnb = (unsigned short*)(ws + OFF_XN);
  unsigned short* w1t = (unsigned short*)(ws + OFF_W1T);
  unsigned short* y   = (unsigned short*)(ws + OFF_W1T);  // overlays w1t after gemm1
  unsigned short* w2t = (unsigned short*)(ws + OFF_W2T);
  unsigned short* h   = (unsigned short*)(ws + OFF_H);
  float* probs        = (float*)(ws + OFF_PROBS);
  int* topi           = (int*)(ws + OFF_TOPI);
  float* topp         = (float*)(ws + OFF_TOPP);
  int* row_token      = (int*)(ws + OFF_ROWTOK);
  float* row_p        = (float*)(ws + OFF_ROWP);
  unsigned* counts    = (unsigned*)(ws + OFF_COUNTS);
  unsigned* cursors   = (unsigned*)(ws + OFF_CURSORS);
  int* ntiles         = (int*)(ws + OFF_NTILES);
  int4* tiles         = (int4*)(ws + OFF_TILES);

  init_kernel<<<1, 64, 0, stream>>>(counts);
  // front: 8192 w1-transpose tiles + 8192 ln/router tokens
  front_kernel<<<16384, 256, 0, stream>>>(x, gamma, beta, rw, rb, xnb, probs,
                                          topi, topp, counts, w1, w1t);
  plan_aux_kernel<<<1, 256, 0, stream>>>(counts, cursors, tiles, ntiles, probs,
                                         out + (size_t)NTOK * DM);
  scatter_kernel<<<NTOK / 256, 256, 0, stream>>>(topi, topp, cursors, row_token, row_p);
  // gemm1 items (4352) + fused w2-transpose (8192 blocks)
  gemm1_kernel<<<GEMM1_BLOCKS + 8192, 256, 0, stream>>>(xnb, w1t, b1, row_token, h,
                                                        tiles, ntiles, w2, w2t);
  gemm2_kernel<<<2176, 256, 0, stream>>>(h, w2t, b2, row_p, tiles, ntiles, y);
  combine_kernel<<<NTOK, 256, 0, stream>>>(x, y, topi, out);
}